// Round 8
// baseline (470.197 us; speedup 1.0000x reference)
//
#include <hip/hip_runtime.h>
#include <hip/hip_bf16.h>

typedef unsigned short u16;
typedef __attribute__((ext_vector_type(8))) short short8;   // 8 bf16 = 4 VGPRs
typedef __attribute__((ext_vector_type(4))) short short4v;  // 4 bf16 = 8 B
typedef __attribute__((ext_vector_type(4))) float floatx4;  // MFMA C/D

#define D_MODEL 1024
#define NH 16
#define SEQ 2048
#define BATCH 4
#define M_ROWS 8192
#define N_QKV 3072
#define PS_LD 72   // Ps row stride (u16): 144 B = 16B-aligned, 4-bank rotate/row

__device__ __forceinline__ u16 f2u(float f) {
    __hip_bfloat16 h = __float2bfloat16(f);
    u16 u; __builtin_memcpy(&u, &h, 2); return u;
}

// ---------------------------------------------------------------------------
// prep: blocks 0..1023 transpose weights to [N][K] bf16 (Wq pre-scaled by
// 0.125); block 1024 packs biases. (x conversion now fused into QKV GEMM.)
// ---------------------------------------------------------------------------
__global__ __launch_bounds__(256) void prep(
    const float* __restrict__ Wq, const float* __restrict__ Wk,
    const float* __restrict__ Wv, const float* __restrict__ Wo,
    const float* __restrict__ bq, const float* __restrict__ bk,
    const float* __restrict__ bv, const float* __restrict__ bo,
    u16* __restrict__ Wpt, u16* __restrict__ Wot, float* __restrict__ biasp)
{
    __shared__ u16 T[64 * 72];
    const int tid = threadIdx.x;
    const int blk = blockIdx.x;

    if (blk == 1024) {                      // biases
        #pragma unroll
        for (int j = 0; j < 16; j++) {
            int idx = j * 256 + tid;
            float v;
            if (idx < 1024)      v = bq[idx] * 0.125f;
            else if (idx < 2048) v = bk[idx - 1024];
            else if (idx < 3072) v = bv[idx - 2048];
            else                 v = bo[idx - 3072];
            biasp[idx] = v;
        }
        return;
    }
    const int r = tid >> 2, s4 = (tid & 3) * 16;
    if (blk < 768) {
        int sel = blk / 256, rem = blk % 256;
        int h = rem >> 4, ktile = rem & 15;
        const float* W = (sel == 0) ? Wq : ((sel == 1) ? Wk : Wv);
        const float scale = (sel == 0) ? 0.125f : 1.0f;
        const float* src = W + ((size_t)h * 1024 + ktile * 64 + r) * 64 + s4;
        #pragma unroll
        for (int i = 0; i < 16; i++) T[(s4 + i) * 72 + r] = f2u(src[i] * scale);
        __syncthreads();
        u16 tmp[16];
        #pragma unroll
        for (int i = 0; i < 16; i++) tmp[i] = T[r * 72 + s4 + i];
        u16* dst = Wpt + ((size_t)sel * 1024 + h * 64 + r) * 1024 + ktile * 64 + s4;
        *(short8*)&dst[0] = *(short8*)&tmp[0];
        *(short8*)&dst[8] = *(short8*)&tmp[8];
    } else {
        int rem = blk - 768;
        int nt = rem >> 4, kt2 = rem & 15;
        const float* src = Wo + ((size_t)kt2 * 64 + r) * 1024 + nt * 64 + s4;
        #pragma unroll
        for (int i = 0; i < 16; i++) T[(s4 + i) * 72 + r] = f2u(src[i]);
        __syncthreads();
        u16 tmp[16];
        #pragma unroll
        for (int i = 0; i < 16; i++) tmp[i] = T[r * 72 + s4 + i];
        u16* dst = Wot + ((size_t)nt * 64 + r) * 1024 + kt2 * 64 + s4;
        *(short8*)&dst[0] = *(short8*)&tmp[0];
        *(short8*)&dst[8] = *(short8*)&tmp[8];
    }
}

// ---------------------------------------------------------------------------
// vtrans: V slice of QKV -> Vtg[bh][d][key] via LDS tile.
// ---------------------------------------------------------------------------
__global__ __launch_bounds__(256) void vtrans(const u16* __restrict__ QKV,
                                              u16* __restrict__ Vtg) {
    __shared__ u16 T[64 * 72];
    const int bh = blockIdx.x, kt = blockIdx.y;
    const int b = bh >> 4, h = bh & 15;
    const int tid = threadIdx.x;
    const int r = tid >> 2, s4 = (tid & 3) * 16;
    const u16* vp = QKV + (size_t)(b * SEQ + kt * 64 + r) * N_QKV + 2 * D_MODEL + h * 64 + s4;
    *(short8*)&T[r * 72 + s4]     = *(const short8*)&vp[0];
    *(short8*)&T[r * 72 + s4 + 8] = *(const short8*)&vp[8];
    __syncthreads();
    u16 tmp[16];
    #pragma unroll
    for (int i = 0; i < 16; i++) tmp[i] = T[(s4 + i) * 72 + r];
    u16* op = Vtg + ((size_t)bh * 64 + r) * SEQ + kt * 64 + s4;
    *(short8*)&op[0] = *(short8*)&tmp[0];
    *(short8*)&op[8] = *(short8*)&tmp[8];
}

// ---------------------------------------------------------------------------
// gemm128 v2: C[M,N] = A[M,K]@Bt[N,K]^T + bias. 128x128 tile, BK=64, 4 waves
// 2x2 of 16-row frags, 16x16x32 bf16 MFMA. Explicit VGPR prefetch of tile
// k+1 issued BEFORE compute(k) (hides global latency behind MFMA; barriers
// wait only on LDS). XOR-swizzled 16B chunks kill stride-128B bank aliasing.
// A may be fp32 (converted during staging) or bf16.
// ---------------------------------------------------------------------------
template <typename AT, typename OT>
__global__ __launch_bounds__(256) void gemm128(
    const AT* __restrict__ A, const u16* __restrict__ Bt,
    const float* __restrict__ bias, OT* __restrict__ C,
    int M, int N, int K)
{
    __shared__ u16 As[128 * 64];
    __shared__ u16 Bs[128 * 64];
    const int tid = threadIdx.x;
    const int w = tid >> 6, lane = tid & 63;
    const int l16 = lane & 15, quad = lane >> 4;
    const int bn = blockIdx.x * 128, bm = blockIdx.y * 128;
    const int wr = (w >> 1) * 64, wc = (w & 1) * 64;

    // staging geometry: thread handles rows rj+{0,32,64,96}, chunk c (8 u16)
    const int rj = tid >> 3, c = tid & 7;

    floatx4 acc[4][4];
    #pragma unroll
    for (int i = 0; i < 4; i++)
        #pragma unroll
        for (int j = 0; j < 4; j++) acc[i][j] = (floatx4){0.f, 0.f, 0.f, 0.f};

    constexpr int AW = (sizeof(AT) == 4) ? 2 : 1;   // float4 loads per A chunk
    float4 areg[4][AW];
    float4 breg[4];

    // ---- load tile k0=0 into regs
    #pragma unroll
    for (int i = 0; i < 4; i++) {
        const int row = rj + i * 32;
        const AT* ap = A + (size_t)(bm + row) * K + c * 8;
        if constexpr (AW == 2) {
            areg[i][0] = *(const float4*)((const float*)ap);
            areg[i][1] = *(const float4*)((const float*)ap + 4);
        } else {
            areg[i][0] = *(const float4*)ap;
        }
        breg[i] = *(const float4*)(Bt + (size_t)(bn + row) * K + c * 8);
    }
    // ---- write to LDS
    #pragma unroll
    for (int i = 0; i < 4; i++) {
        const int row = rj + i * 32;
        const int slot = (c ^ (row & 7)) * 8;
        if constexpr (AW == 2) {
            const float* f0 = (const float*)&areg[i][0];
            const float* f1 = (const float*)&areg[i][1];
            u16 t[8] = {f2u(f0[0]), f2u(f0[1]), f2u(f0[2]), f2u(f0[3]),
                        f2u(f1[0]), f2u(f1[1]), f2u(f1[2]), f2u(f1[3])};
            *(float4*)&As[row * 64 + slot] = *(float4*)t;
        } else {
            *(float4*)&As[row * 64 + slot] = areg[i][0];
        }
        *(float4*)&Bs[row * 64 + slot] = breg[i];
    }
    __syncthreads();

    for (int k0 = 0; k0 < K; k0 += 64) {
        const bool pre = (k0 + 64 < K);
        if (pre) {      // prefetch next tile (no wait — hidden by compute)
            #pragma unroll
            for (int i = 0; i < 4; i++) {
                const int row = rj + i * 32;
                const AT* ap = A + (size_t)(bm + row) * K + k0 + 64 + c * 8;
                if constexpr (AW == 2) {
                    areg[i][0] = *(const float4*)((const float*)ap);
                    areg[i][1] = *(const float4*)((const float*)ap + 4);
                } else {
                    areg[i][0] = *(const float4*)ap;
                }
                breg[i] = *(const float4*)(Bt + (size_t)(bn + row) * K + k0 + 64 + c * 8);
            }
        }

        #pragma unroll
        for (int kc = 0; kc < 2; kc++) {
            short8 a[4], b[4];
            #pragma unroll
            for (int i = 0; i < 4; i++) {
                const int ra = wr + i * 16 + l16;
                a[i] = *(short8*)&As[ra * 64 + ((kc * 4 + quad) ^ (ra & 7)) * 8];
                const int rb = wc + i * 16 + l16;
                b[i] = *(short8*)&Bs[rb * 64 + ((kc * 4 + quad) ^ (rb & 7)) * 8];
            }
            #pragma unroll
            for (int mm = 0; mm < 4; mm++)
                #pragma unroll
                for (int nn = 0; nn < 4; nn++)
                    acc[mm][nn] = __builtin_amdgcn_mfma_f32_16x16x32_bf16(
                        a[mm], b[nn], acc[mm][nn], 0, 0, 0);
        }

        if (pre) {
            __syncthreads();       // all waves done reading this tile
            #pragma unroll
            for (int i = 0; i < 4; i++) {
                const int row = rj + i * 32;
                const int slot = (c ^ (row & 7)) * 8;
                if constexpr (AW == 2) {
                    const float* f0 = (const float*)&areg[i][0];
                    const float* f1 = (const float*)&areg[i][1];
                    u16 t[8] = {f2u(f0[0]), f2u(f0[1]), f2u(f0[2]), f2u(f0[3]),
                                f2u(f1[0]), f2u(f1[1]), f2u(f1[2]), f2u(f1[3])};
                    *(float4*)&As[row * 64 + slot] = *(float4*)t;
                } else {
                    *(float4*)&As[row * 64 + slot] = areg[i][0];
                }
                *(float4*)&Bs[row * 64 + slot] = breg[i];
            }
            __syncthreads();       // writes visible (lgkmcnt only)
        }
    }

    #pragma unroll
    for (int nn = 0; nn < 4; nn++) {
        const int col = bn + wc + nn * 16 + l16;
        const float bi = bias[col];
        #pragma unroll
        for (int mm = 0; mm < 4; mm++) {
            const int row = bm + wr + mm * 16 + quad * 4;
            #pragma unroll
            for (int r = 0; r < 4; r++) {
                float v = acc[mm][nn][r] + bi;
                if constexpr (sizeof(OT) == 2) ((u16*)C)[(size_t)(row + r) * N + col] = f2u(v);
                else                           C[(size_t)(row + r) * N + col] = v;
            }
        }
    }
}

// ---------------------------------------------------------------------------
// attn_mfma: transposed-S flash attention + XOR-swizzled K/V LDS staging +
// double-buffered tiles (1 barrier/tile). Block = (bh, 128 q-rows),
// 4 waves x 32 q-rows, K-tile 64. (Round-7 verified.)
// ---------------------------------------------------------------------------
__global__ __launch_bounds__(256) void attn_mfma(
    const u16* __restrict__ QKV, const u16* __restrict__ Vtg, u16* __restrict__ ctx)
{
    __shared__ u16 Ks[2][64 * 64];   // [key][d], chunk-swizzled
    __shared__ u16 Vs[2][64 * 64];   // [d][key], chunk-swizzled
    __shared__ u16 Ps[128 * PS_LD];  // [qrow][key]

    const int bh = blockIdx.x;
    const int qt = (int)(gridDim.y - 1) - (int)blockIdx.y;   // long blocks first
    const int b = bh >> 4, h = bh & 15;
    const int tid = threadIdx.x;
    const int w = tid >> 6, lane = tid & 63;
    const int l16 = lane & 15, quad = lane >> 4;

    const int r0 = tid >> 3,         c0 = tid & 7;
    const int r1 = (256 + tid) >> 3, c1 = tid & 7;
    const int sw0 = c0 ^ (r0 & 7), sw1 = c1 ^ (r1 & 7);

    short8 q[2][2];
    #pragma unroll
    for (int m = 0; m < 2; m++) {
        const u16* qp = QKV + (size_t)(b * SEQ + qt * 128 + w * 32 + m * 16 + l16) * N_QKV + h * 64;
        q[m][0] = *(const short8*)&qp[quad * 8];
        q[m][1] = *(const short8*)&qp[32 + quad * 8];
    }

    floatx4 O[2][4];
    #pragma unroll
    for (int m = 0; m < 2; m++)
        #pragma unroll
        for (int i = 0; i < 4; i++) O[m][i] = (floatx4){0.f, 0.f, 0.f, 0.f};
    float li[2] = {0.f, 0.f};

    const int nkt = 2 * qt + 2;
    const int qrow_w_max = qt * 128 + w * 32 + 31;

    const size_t kbase = (size_t)(b * SEQ) * N_QKV + D_MODEL + h * 64;
    const size_t vbase = (size_t)bh * 64 * SEQ;

    {
        float4 ka = *(const float4*)(QKV + kbase + (size_t)r0 * N_QKV + c0 * 8);
        float4 kb = *(const float4*)(QKV + kbase + (size_t)r1 * N_QKV + c1 * 8);
        float4 va = *(const float4*)(Vtg + vbase + (size_t)r0 * SEQ + c0 * 8);
        float4 vb = *(const float4*)(Vtg + vbase + (size_t)r1 * SEQ + c1 * 8);
        *(float4*)&Ks[0][r0 * 64 + sw0 * 8] = ka;
        *(float4*)&Ks[0][r1 * 64 + sw1 * 8] = kb;
        *(float4*)&Vs[0][r0 * 64 + sw0 * 8] = va;
        *(float4*)&Vs[0][r1 * 64 + sw1 * 8] = vb;
    }
    __syncthreads();

    for (int kt = 0; kt < nkt; kt++) {
        const int buf = kt & 1;
        const bool pre = (kt + 1 < nkt);
        float4 ka, kb, va, vb;
        if (pre) {
            const int t1 = (kt + 1) * 64;
            ka = *(const float4*)(QKV + kbase + (size_t)(t1 + r0) * N_QKV + c0 * 8);
            kb = *(const float4*)(QKV + kbase + (size_t)(t1 + r1) * N_QKV + c1 * 8);
            va = *(const float4*)(Vtg + vbase + (size_t)r0 * SEQ + t1 + c0 * 8);
            vb = *(const float4*)(Vtg + vbase + (size_t)r1 * SEQ + t1 + c1 * 8);
        }

        if (kt * 64 <= qrow_w_max) {
            short8 kf[4][2];
            #pragma unroll
            for (int ns = 0; ns < 4; ns++) {
                const int rr = ns * 16 + l16, rs = rr & 7;
                kf[ns][0] = *(short8*)&Ks[buf][rr * 64 + (quad ^ rs) * 8];
                kf[ns][1] = *(short8*)&Ks[buf][rr * 64 + ((4 + quad) ^ rs) * 8];
            }
            const bool needMask = (kt * 64 + 63 > qt * 128 + w * 32);

            #pragma unroll
            for (int m = 0; m < 2; m++) {
                floatx4 z[4];
                #pragma unroll
                for (int ns = 0; ns < 4; ns++) {
                    floatx4 t = (floatx4){0.f, 0.f, 0.f, 0.f};
                    t = __builtin_amdgcn_mfma_f32_16x16x32_bf16(kf[ns][0], q[m][0], t, 0, 0, 0);
                    t = __builtin_amdgcn_mfma_f32_16x16x32_bf16(kf[ns][1], q[m][1], t, 0, 0, 0);
                    z[ns] = t;
                }
                const int qrow_g = qt * 128 + w * 32 + m * 16 + l16;
                const int prow = (w * 32 + m * 16 + l16) * PS_LD;
                float sum = 0.f;
                #pragma unroll
                for (int ns = 0; ns < 4; ns++) {
                    u16 pk[4];
                    #pragma unroll
                    for (int r = 0; r < 4; r++) {
                        float s = z[ns][r];
                        const int key = kt * 64 + ns * 16 + quad * 4 + r;
                        if (needMask && key > qrow_g) s = -INFINITY;
                        float p = __expf(s - 8.0f);
                        pk[r] = f2u(p);
                        sum += p;
                    }
                    *(short4v*)&Ps[prow + ns * 16 + quad * 4] = *(short4v*)pk;
                }
                sum += __shfl_xor(sum, 16);
                sum += __shfl_xor(sum, 32);
                li[m] += sum;
            }

            short8 vf[4][2];
            #pragma unroll
            for (int ds = 0; ds < 4; ds++) {
                const int rr = ds * 16 + l16, rs = rr & 7;
                vf[ds][0] = *(short8*)&Vs[buf][rr * 64 + (quad ^ rs) * 8];
                vf[ds][1] = *(short8*)&Vs[buf][rr * 64 + ((4 + quad) ^ rs) * 8];
            }
            #pragma unroll
            for (int m = 0; m < 2; m++) {
                const int prow = (w * 32 + m * 16 + l16) * PS_LD;
                short8 p0 = *(short8*)&Ps[prow + quad * 8];
                short8 p1 = *(short8*)&Ps[prow + 32 + quad * 8];
                #pragma unroll
                for (int ds = 0; ds < 4; ds++) {
                    O[m][ds] = __builtin_amdgcn_mfma_f32_16x16x32_bf16(vf[ds][0], p0, O[m][ds], 0, 0, 0);
                    O[m][ds] = __builtin_amdgcn_mfma_f32_16x16x32_bf16(vf[ds][1], p1, O[m][ds], 0, 0, 0);
                }
            }
        }

        if (pre) {
            const int nb = buf ^ 1;
            *(float4*)&Ks[nb][r0 * 64 + sw0 * 8] = ka;
            *(float4*)&Ks[nb][r1 * 64 + sw1 * 8] = kb;
            *(float4*)&Vs[nb][r0 * 64 + sw0 * 8] = va;
            *(float4*)&Vs[nb][r1 * 64 + sw1 * 8] = vb;
        }
        __syncthreads();
    }

    #pragma unroll
    for (int m = 0; m < 2; m++) {
        const float inv = 1.0f / li[m];
        const size_t base = (size_t)(b * SEQ + qt * 128 + w * 32 + m * 16 + l16) * D_MODEL + h * 64;
        #pragma unroll
        for (int ds = 0; ds < 4; ds++) {
            u16 o[4];
            #pragma unroll
            for (int r = 0; r < 4; r++) o[r] = f2u(O[m][ds][r] * inv);
            *(short4v*)&ctx[base + ds * 16 + quad * 4] = *(short4v*)o;
        }
    }
}

// ---------------------------------------------------------------------------
extern "C" void kernel_launch(void* const* d_in, const int* in_sizes, int n_in,
                              void* d_out, int out_size, void* d_ws, size_t ws_size,
                              hipStream_t stream) {
    const float* x  = (const float*)d_in[0];
    const float* Wq = (const float*)d_in[1];
    const float* bq = (const float*)d_in[2];
    const float* Wk = (const float*)d_in[3];
    const float* bk = (const float*)d_in[4];
    const float* Wv = (const float*)d_in[5];
    const float* bv = (const float*)d_in[6];
    const float* Wo = (const float*)d_in[7];
    const float* bo = (const float*)d_in[8];
    float* out = (float*)d_out;

    // workspace (bytes): total 0x5840000 = 92.3 MB
    char* ws = (char*)d_ws;
    float* biasp = (float*)ws;                       // 16 KB
    u16*   Wpt   = (u16*)(ws + 0x10000);             // 6 MB  [3072][1024]
    u16*   Wot   = (u16*)(ws + 0x620000);            // 2 MB  [1024][1024]
    u16*   QKV   = (u16*)(ws + 0x840000);            // 48 MB [8192][3072]
    u16*   Vtg   = (u16*)(ws + 0x3840000);           // 16 MB [64*64][2048]
    u16*   ctx   = (u16*)(ws + 0x4840000);           // 16 MB [8192][1024]

    prep<<<1025, 256, 0, stream>>>(Wq, Wk, Wv, Wo, bq, bk, bv, bo,
                                   Wpt, Wot, biasp);

    // QKV projection: x fp32 converted in-staging
    gemm128<float, u16><<<dim3(N_QKV / 128, M_ROWS / 128), 256, 0, stream>>>(
        x, Wpt, biasp, QKV, M_ROWS, N_QKV, D_MODEL);

    vtrans<<<dim3(64, 32), 256, 0, stream>>>(QKV, Vtg);

    attn_mfma<<<dim3(BATCH * NH, SEQ / 128), 256, 0, stream>>>(QKV, Vtg, ctx);

    gemm128<u16, float><<<dim3(D_MODEL / 128, M_ROWS / 128), 256, 0, stream>>>(
        ctx, Wot, biasp + N_QKV, out, M_ROWS, D_MODEL, D_MODEL);
}